// Round 13
// baseline (329.556 us; speedup 1.0000x reference)
//
#include <hip/hip_runtime.h>
#include <hip/hip_bf16.h>

typedef __attribute__((ext_vector_type(8))) short bf16x8;
typedef __attribute__((ext_vector_type(4))) short bf16x4;
typedef __attribute__((ext_vector_type(4))) float f32x4;
typedef __attribute__((address_space(3))) ushort lds_ushort;

#define MFMA32(a, b, c) __builtin_amdgcn_mfma_f32_16x16x32_bf16(a, b, c, 0, 0, 0)
#if __has_builtin(__builtin_amdgcn_mfma_f32_16x16x16bf16_1k)
#define HAVE_MFMA16K 1
#define MFMA16K(a, b, c) __builtin_amdgcn_mfma_f32_16x16x16bf16_1k(a, b, c, 0, 0, 0)
#else
#define HAVE_MFMA16K 0
#endif

// async global->LDS, 16B/lane; LDS dest = wave-uniform base + lane*16.
#define ASYNC16(g, l)                                                          \
    __builtin_amdgcn_global_load_lds(                                          \
        (const __attribute__((address_space(1))) unsigned int*)(g),            \
        (__attribute__((address_space(3))) unsigned int*)(l), 16, 0, 0)

// hw transpose read: per 16-lane group reads 128B window as 4x16 bf16
// row-major, lane l gets column (l&15). addr = window_base + (l&15)*8 bytes.
#define TR16(dst, addr, OFF)                                                   \
    asm volatile("ds_read_b64_tr_b16 %0, %1 offset:%2"                         \
                 : "=v"(dst) : "v"(addr), "i"(OFF))

__device__ __forceinline__ ushort f2bf(float f) {
    __hip_bfloat16 h = __float2bfloat16(f);  // RNE
    return *reinterpret_cast<ushort*>(&h);
}
// pack two f32 to bf16 pair in one instruction (T12; no builtin on gfx950).
__device__ __forceinline__ uint cvtpk(float a, float b) {
    uint r;
    asm("v_cvt_pk_bf16_f32 %0, %1, %2" : "=v"(r) : "v"(a), "v"(b));
    return r;
}

// log2(e)/sqrt(64), folded into Q projection -> attn does exp2(score) raw.
#define QSCALE 0.18033688011112042f

// ---------------------------------------------------------------------------
// fp32 -> bf16 convert, multi-range (q,k,v + 4 weights).
// ---------------------------------------------------------------------------
struct CvtArgs { const float* s[7]; ushort* d[7]; int nb[7]; };

__global__ __launch_bounds__(256) void cvtk(CvtArgs a) {
    const int z = blockIdx.y;
    if ((int)blockIdx.x >= a.nb[z]) return;
    const float* s = a.s[z];
    ushort* d = a.d[z];
    const size_t i = (size_t)blockIdx.x * 2048 + threadIdx.x * 8;
    float4 f0 = *(const float4*)&s[i];
    float4 f1 = *(const float4*)&s[i + 4];
    *(ushort4*)&d[i]     = make_ushort4(f2bf(f0.x), f2bf(f0.y), f2bf(f0.z), f2bf(f0.w));
    *(ushort4*)&d[i + 4] = make_ushort4(f2bf(f1.x), f2bf(f1.y), f2bf(f1.z), f2bf(f1.w));
}

// ---------------------------------------------------------------------------
// 128x128 counted-vmcnt bf16 NT GEMM: out = (X@W^T + bias) * scale
//   mode 0: bf16 out [B=4,H=16,S=2048,64]; mode 2: fp32 out [8192,1024].
// R12: ONE phase per tile with 16 MFMA (R11 had 2 phases x 8) — barrier
// count halves again (64 -> 32/block); R10->R11 proved the phases are
// barrier-overhead-dominated (-18.8us). The R11 2-phase split existed only
// because t+2's B landed in the currently-read B buffer; fix = TRIPLE-buffer
// B (bufB[t%3]): t+2's DMA goes to (t+2)%3 != t%3, != (t+1)%3. A stays
// double-buffered (issued 1-ahead, opposite buffer). LDS = 2x16KB(A) +
// 3x16KB(B) = 80KB = exactly 2 blocks/CU (launch_bounds(512,4)).
// Per tile t: {issueA(t+1); issueB(t+2); ds_read 4 B-frags + 8 A-frags} ->
// barrier -> lgkmcnt(0) -> setprio(1) -> 16 MFMA -> setprio(0) -> vmcnt ->
// barrier.
// vmcnt ledger (issueA=2, issueB=2 loads/thread): prologue B(0),A(0),B(1)=6,
// vmcnt(2) lands tile0, leaves B(1). Tile t: queue [B(t+1),A(t+1)] + issue
// [A? no:] entering t queue = [B(t+1)]; after issues = [B(t+1), A(t+1),
// B(t+2)] = 6; vmcnt(2) retires B(t+1)+A(t+1) = tile t+1 complete, leaves
// B(t+2). t>=14: issueB skipped (tile>=16) -> only 4 outstanding -> full
// drain vmcnt(0) (tail-race rule from R7).
// Buffer hazards: DMA target's previous occupant is tile t-1, whose reads
// were lgkm-drained before t-1's trailing barrier; issue is >=1 barrier
// later (cross-wave safe). Bank swizzle: phys 16B-group = logical^(row&7)
// on DMA source and reads (row&7 == l16&7 at every read site).
// XCD: t0=(flat&7)*64+flat>>3 (bijective, 512%8==0).
// ---------------------------------------------------------------------------
struct GemmArgs {
    const ushort* X[3]; const ushort* W[3]; const float* B[3];
    void* O[3]; int mode[3]; float scale[3];
};

__global__ __launch_bounds__(512, 4) void gemmk(GemmArgs g) {
    extern __shared__ __attribute__((aligned(16))) ushort smem[];
    // A: [0, 16384) ushorts (2 bufs x 8192); B: [16384, 40960) (3 x 8192).

    const int z = blockIdx.z;
    const ushort* __restrict__ X = g.X[z];
    const ushort* __restrict__ W = g.W[z];
    const float*  __restrict__ bias = g.B[z];
    const int mode = g.mode[z];
    const float scale = g.scale[z];

    const int tid  = threadIdx.x;
    const int lane = tid & 63;
    const int wave = tid >> 6;
    const int quad = (lane >> 4) & 3;
    const int l16  = lane & 15;
    const int wm   = (wave >> 2) * 64;   // 2 M-waves: 64 rows each
    const int wn   = (wave & 3) * 32;    // 4 N-waves: 32 cols each

    const int flat = blockIdx.x + 8 * blockIdx.y;     // 0..511, xcd = flat%8
    const int t0   = (flat & 7) * 64 + (flat >> 3);   // bijective (512%8==0)
    const int m0   = (t0 >> 3) * 128;
    const int n0   = (t0 & 7) * 128;

    f32x4 acc[4][2];
#pragma unroll
    for (int i = 0; i < 4; i++)
#pragma unroll
        for (int j = 0; j < 2; j++) acc[i][j] = (f32x4)0.0f;

    // Full A tile (128x64 = 16KB = 1024 chunks) -> 2 loads/thread.
    // Row-major [128][64] with group swizzle: phys gp = (c&7)^(row&7).
    auto issueA = [&](int tile) {
        if (tile >= 16) return;
        const int k0 = tile * 64;
        ushort* dst = smem + (tile & 1) * 8192;
#pragma unroll
        for (int j = 0; j < 2; j++) {
            const int c   = j * 512 + tid;
            const int row = c >> 3;
            const int gp  = (c & 7) ^ (row & 7);
            ASYNC16(&X[(size_t)(m0 + row) * 1024 + k0 + gp * 8],
                    dst + (size_t)(j * 512 + wave * 64) * 8);
        }
    };
    // Full B tile (128x64 = 16KB) -> 2 loads/thread, triple-buffered.
    auto issueB = [&](int tile) {
        if (tile >= 16) return;
        const int k0 = tile * 64;
        ushort* dst = smem + 16384 + (tile % 3) * 8192;
#pragma unroll
        for (int j = 0; j < 2; j++) {
            const int c   = j * 512 + tid;
            const int row = c >> 3;
            const int gp  = (c & 7) ^ (row & 7);
            ASYNC16(&W[(size_t)(n0 + row) * 1024 + k0 + gp * 8],
                    dst + (size_t)(j * 512 + wave * 64) * 8);
        }
    };

    // Prologue: B(0), A(0), B(1) = 6 loads; land tile0, leave B(1) in flight.
    issueB(0);
    issueA(0);
    issueB(1);
    asm volatile("s_waitcnt vmcnt(2)" ::: "memory");
    __builtin_amdgcn_sched_barrier(0);
    __builtin_amdgcn_s_barrier();

    const int sw = l16 & 7;

    for (int t = 0; t < 16; t++) {
        const ushort* A  = smem + (t & 1) * 8192;
        const ushort* Bm = smem + 16384 + (t % 3) * 8192;

        issueA(t + 1);
        issueB(t + 2);

        bf16x8 bfrag[2][2];
#pragma unroll
        for (int nj = 0; nj < 2; nj++)
#pragma unroll
            for (int ks = 0; ks < 2; ks++) {
                const int br = wn + nj * 16 + l16;
                bfrag[nj][ks] = *(const bf16x8*)
                    &Bm[(size_t)br * 64 + (((ks * 4 + quad) ^ sw) * 8)];
            }
        bf16x8 af[4][2];
#pragma unroll
        for (int i = 0; i < 4; i++)
#pragma unroll
            for (int ks = 0; ks < 2; ks++) {
                const int ar = wm + i * 16 + l16;
                af[i][ks] = *(const bf16x8*)
                    &A[(size_t)ar * 64 + (((ks * 4 + quad) ^ sw) * 8)];
            }

        __builtin_amdgcn_s_barrier();
        asm volatile("s_waitcnt lgkmcnt(0)" ::: "memory");
        __builtin_amdgcn_sched_barrier(0);
        __builtin_amdgcn_s_setprio(1);
#pragma unroll
        for (int i = 0; i < 4; i++)
#pragma unroll
            for (int nj = 0; nj < 2; nj++) {
                acc[i][nj] = MFMA32(af[i][0], bfrag[nj][0], acc[i][nj]);
                acc[i][nj] = MFMA32(af[i][1], bfrag[nj][1], acc[i][nj]);
            }
        __builtin_amdgcn_s_setprio(0);
        if (t < 14) {
            // tile t+1 fully landed; t+2's B stays in flight.
            asm volatile("s_waitcnt vmcnt(2)" ::: "memory");
        } else {
            // issue stream exhausted: full drain (tail-race rule).
            asm volatile("s_waitcnt vmcnt(0)" ::: "memory");
        }
        __builtin_amdgcn_sched_barrier(0);
        __builtin_amdgcn_s_barrier();
    }

    // C/D: col = lane&15 (n), row = quad*4 + reg (m).
#pragma unroll
    for (int mi = 0; mi < 4; mi++) {
#pragma unroll
        for (int nj = 0; nj < 2; nj++) {
            const int n  = n0 + wn + nj * 16 + l16;
            const float bb = bias[n];
#pragma unroll
            for (int r = 0; r < 4; r++) {
                const int m = m0 + wm + mi * 16 + quad * 4 + r;
                const float val = (acc[mi][nj][r] + bb) * scale;
                if (mode == 2) {
                    ((float*)g.O[z])[(size_t)m * 1024 + n] = val;
                } else {
                    const int bat = m >> 11, s = m & 2047, h = n >> 6, d = n & 63;
                    ((ushort*)g.O[z])[((size_t)((bat * 16 + h) * 2048 + s)) * 64 + d]
                        = f2bf(val);
                }
            }
        }
    }
}

// ---------------------------------------------------------------------------
// Attention — VERBATIM R8/R10/R11 version (harness-passed at ~92 us; ~97%
// combined MFMA+VALU issue = structural ceiling). st=2, grid 1024, 4/CU.
// ---------------------------------------------------------------------------
__global__ __launch_bounds__(256, 4) void attn(
    const ushort* __restrict__ Qp, const ushort* __restrict__ Kp,
    const ushort* __restrict__ Vp, ushort* __restrict__ ctx)
{
    __shared__ __attribute__((aligned(16))) ushort Ks[2][2 * 64 * 32];  // 2x8KB
    __shared__ __attribute__((aligned(16))) ushort Vs[2][64 * 64];      // 2x8KB

    const int tid  = threadIdx.x;
    const int lane = tid & 63;
    const int wave = tid >> 6;
    const int quad = lane >> 4;
    const int l16  = lane & 15;

    const int id = blockIdx.x;
    const int bh = (id & 7) * 8 + ((id >> 3) & 7);  // XCD-contiguous bh
    const int q0 = (id >> 6) * 128;
    const int b  = bh >> 4, h = bh & 15;

    const ushort* Qg = Qp + ((size_t)bh * 2048 + q0) * 64;
    const ushort* Kg = Kp + (size_t)bh * 2048 * 64;
    const ushort* Vg = Vp + (size_t)bh * 2048 * 64;

    // Loop-invariant Q fragments (B-operand: n=l16=query, k=quad*8+e).
    bf16x8 aq[2][2];
#pragma unroll
    for (int st = 0; st < 2; st++)
#pragma unroll
        for (int kk = 0; kk < 2; kk++)
            aq[st][kk] = *(const bf16x8*)&Qg[(size_t)(wave * 32 + st * 16 + l16) * 64
                                            + kk * 32 + quad * 8];

    f32x4 o[2][4];
#pragma unroll
    for (int st = 0; st < 2; st++)
#pragma unroll
        for (int jd = 0; jd < 4; jd++) o[st][jd] = (f32x4)0.0f;
#if HAVE_MFMA16K
    f32x4 ls[2] = {(f32x4)0.0f, (f32x4)0.0f};  // row sums, o-compatible layout
    union { uint u[2]; bf16x4 v; } ones;
    ones.u[0] = 0x3F803F80u; ones.u[1] = 0x3F803F80u;  // bf16 1.0 x4
#else
    float lsum[2] = {0.f, 0.f};
#endif

    // K tile: natural [half][row][32] layout. V tile: 4x16-subtiled V' via
    // source-swizzled async chunks; global src stays 128B-coalesced per 8 lanes.
    auto stage = [&](int buf, int n0) {
#pragma unroll
        for (int j = 0; j < 2; j++) {
            const int c    = j * 256 + tid;
            const int colq = c & 3;
            const int row  = (c >> 2) & 63;
            const int half = c >> 8;
            ASYNC16(&Kg[(size_t)(n0 + row) * 64 + half * 32 + colq * 8],
                    &Ks[buf][0] + (size_t)(j * 256 + wave * 64) * 8);
        }
#pragma unroll
        for (int j = 0; j < 2; j++) {
            const int c   = j * 256 + tid;
            const int key = ((c >> 5) << 2) | ((c >> 1) & 3);
            const int d   = (((c >> 3) & 3) << 4) | ((c & 1) << 3);
            ASYNC16(&Vg[(size_t)(n0 + key) * 64 + d],
                    &Vs[buf][0] + (size_t)(j * 256 + wave * 64) * 8);
        }
    };

    stage(0, 0);
    int cur = 0;

    for (int n0 = 0; n0 < 2048; n0 += 64) {
        __syncthreads();  // drains vmcnt: buf 'cur' is ready; prev reads done
        if (n0 + 64 < 2048) stage(cur ^ 1, n0 + 64);  // flies under compute

        // ---- S^T: 8 tiles (kb keys x st strips), exp2 + pack in-register ----
        uint pk[4][2][2];
#pragma unroll
        for (int kb = 0; kb < 4; kb++) {
            bf16x8 kf0 = *(const bf16x8*)&Ks[cur][(size_t)(kb * 16 + l16) * 32 + quad * 8];
            bf16x8 kf1 = *(const bf16x8*)&Ks[cur][(size_t)(64 + kb * 16 + l16) * 32 + quad * 8];
#pragma unroll
            for (int st = 0; st < 2; st++) {
                f32x4 s = (f32x4)0.0f;
                s = MFMA32(kf0, aq[st][0], s);
                s = MFMA32(kf1, aq[st][1], s);
                float e0 = __builtin_amdgcn_exp2f(s[0]);
                float e1 = __builtin_amdgcn_exp2f(s[1]);
                float e2 = __builtin_amdgcn_exp2f(s[2]);
                float e3 = __builtin_amdgcn_exp2f(s[3]);
                pk[kb][st][0] = cvtpk(e0, e1);
                pk[kb][st][1] = cvtpk(e2, e3);
#if !HAVE_MFMA16K
                lsum[st] += (e0 + e1) + (e2 + e3);
#endif
            }
        }

#if HAVE_MFMA16K
        // ---- PV: B-frags via hw transpose reads from subtiled V' ----
        const lds_ushort* vp = (const lds_ushort*)&Vs[cur][0] + quad * 256 + l16 * 4;
        bf16x4 vf[4][4];  // [jd][kb]
#define TRISSUE(JD)                                                            \
        TR16(vf[JD][0], vp, (JD) * 128 + 0);                                   \
        TR16(vf[JD][1], vp, (JD) * 128 + 2048);                                \
        TR16(vf[JD][2], vp, (JD) * 128 + 4096);                                \
        TR16(vf[JD][3], vp, (JD) * 128 + 6144);
        TRISSUE(0) TRISSUE(1) TRISSUE(2) TRISSUE(3)

        // Row-sum MFMAs (register-only) fill the tr-read latency window.
#pragma unroll
        for (int kb = 0; kb < 4; kb++) {
#pragma unroll
            for (int st = 0; st < 2; st++) {
                union { uint u[2]; bf16x4 v; } pf;
                pf.u[0] = pk[kb][st][0];
                pf.u[1] = pk[kb][st][1];
                ls[st] = MFMA16K(pf.v, ones.v, ls[st]);
            }
        }

        // counted lgkmcnt: jd group ready when <=12-4*jd outstanding (FIFO,
        // trs are oldest). sched_barrier(0) after each wait (rule #18).
#define PVWAIT(N)                                                              \
        asm volatile("s_waitcnt lgkmcnt(" #N ")" ::: "memory");                \
        __builtin_amdgcn_sched_barrier(0);
#define PVJD(JD)                                                               \
        _Pragma("unroll")                                                      \
        for (int kb = 0; kb < 4; kb++) {                                       \
            _Pragma("unroll")                                                  \
            for (int st = 0; st < 2; st++) {                                   \
                union { uint u[2]; bf16x4 v; } pf;                             \
                pf.u[0] = pk[kb][st][0];                                       \
                pf.u[1] = pk[kb][st][1];                                       \
                o[st][JD] = MFMA16K(pf.v, vf[JD][kb], o[st][JD]);              \
            }                                                                  \
        }
        __builtin_amdgcn_s_setprio(1);
        PVWAIT(12) PVJD(0)
        PVWAIT(8)  PVJD(1)
        PVWAIT(4)  PVJD(2)
        PVWAIT(0)  PVJD(3)
        __builtin_amdgcn_s_setprio(0);
#else
        // Fallback: assemble K=32 A-frags via ds_bpermute, gather V from the
        // subtiled V' with scalar reads, PV with MFMA32. (Correctness path.)
        const int addr0 = 4 * ((2 * (quad & 1)) * 16 + l16);
        const int addr1 = addr0 + 64;
#pragma unroll
        for (int kt = 0; kt < 2; kt++) {
            bf16x8 apf[2];
#pragma unroll
            for (int st = 0; st < 2; st++) {
                union { uint u[4]; bf16x8 v; } t;
#pragma unroll
                for (int j = 0; j < 4; j++) {
                    uint src = (quad & 2) ? pk[kt * 2 + 1][st][j & 1]
                                          : pk[kt * 2][st][j & 1];
                    t.u[j] = (uint)__builtin_amdgcn_ds_bpermute(
                        (j >> 1) ? addr1 : addr0, (int)src);
                }
                apf[st] = t.v;
            }
#pragma unroll
            for (int jd = 0; jd < 4; jd++) {
                union { ushort s[8]; bf16x8 v; } vv;
#pragma unroll
                for (int e = 0; e < 8; e++) {
                    const int key = kt * 32 + quad * 8 + e;
                    const int d   = jd * 16 + l16;
                    vv.s[e] = Vs[cur][(key >> 2) * 256 + (d >> 4) * 64
                                      + (key & 3) * 16 + (d & 15)];
                }
#pragma unroll
                for (int st = 0; st < 2; st++)
                    o[st][jd] = MFMA32(apf[st], vv.v, o[st][jd]);
            }
        }
#endif
        cur ^= 1;
    }

#if HAVE_MFMA16K
    // ls[st][r] is already the row sum for query quad*4+r — no shuffles.
#pragma unroll
    for (int st = 0; st < 2; st++) {
        float inv[4];
#pragma unroll
        for (int r = 0; r < 4; r++) inv[r] = 1.0f / ls[st][r];
#pragma unroll
        for (int jd = 0; jd < 4; jd++) {
#pragma unroll
            for (int r = 0; r < 4; r++) {
                const int s = q0 + wave * 32 + st * 16 + quad * 4 + r;
                ctx[((size_t)(b * 2048 + s)) * 1024 + h * 64 + jd * 16 + l16] =
                    f2bf(o[st][jd][r] * inv[r]);
            }
        }
    }
#else
    // lsum holds per-(l16,quad) partials for query=l16: reduce over quads.
#pragma unroll
    for (int st = 0; st < 2; st++) {
        float lsv = lsum[st];
        lsv += __shfl_xor(lsv, 16, 64);
        lsv += __shfl_xor(lsv, 32, 64);
        float inv[4];
#pragma unroll
        for (int r = 0; r < 4; r++)
            inv[r] = 1.0f / __shfl(lsv, quad * 4 + r, 64);
#pragma unroll
        for (int jd = 0; jd < 4; jd++) {
#pragma unroll
            for (int r = 0; r < 4; r++) {
                const int s = q0 + wave * 32 + st * 16 + quad * 4 + r;
                ctx[((size_t)(b * 2048 + s)) * 1024 + h * 64 + jd * 16 + l16] =
                    f2bf(o[st][jd][r] * inv[r]);
            }
        }
    }
#endif
}

extern "C" void kernel_launch(void* const* d_in, const int* in_sizes, int n_in,
                              void* d_out, int out_size, void* d_ws, size_t ws_size,
                              hipStream_t stream) {
    const float* q    = (const float*)d_in[0];
    const float* k    = (const float*)d_in[1];
    const float* v    = (const float*)d_in[2];
    const float* wq_w = (const float*)d_in[3];
    const float* wq_b = (const float*)d_in[4];
    const float* wk_w = (const float*)d_in[5];
    const float* wk_b = (const float*)d_in[6];
    const float* wv_w = (const float*)d_in[7];
    const float* wv_b = (const float*)d_in[8];
    const float* wo_w = (const float*)d_in[9];
    const float* wo_b = (const float*)d_in[10];
    float* out = (float*)d_out;

    const size_t NE = (size_t)4 * 2048 * 1024;
    const size_t NW = (size_t)1024 * 1024;
    const size_t need_fused = (6 * NE + 4 * NW) * 2;
    const size_t LDSB = 81920;  // 80KB dynamic LDS for gemmk -> 2 blocks/CU

    dim3 blk(256);
    dim3 gblk(512);
    dim3 ggrid(8, 64, 3);   // 512 wgs/z: 64 m-tiles x 8 n-tiles
    dim3 ggrid1(8, 64, 1);

    if (ws_size >= need_fused) {
        ushort* Xq = (ushort*)d_ws;
        ushort* Xk = Xq + NE;
        ushort* Xv = Xk + NE;
        ushort* Wq = Xv + NE;
        ushort* Wk = Wq + NW;
        ushort* Wv = Wk + NW;
        ushort* Wo = Wv + NW;
        ushort* Qp = Wo + NW;
        ushort* Kp = Qp + NE;
        ushort* Vp = Kp + NE;
        ushort* ctx = Xq;

        CvtArgs ca;
        ca.s[0]=q;    ca.d[0]=Xq; ca.nb[0]=4096;
        ca.s[1]=k;    ca.d[1]=Xk; ca.nb[1]=4096;
        ca.s[2]=v;    ca.d[2]=Xv; ca.nb[2]=4096;
        ca.s[3]=wq_w; ca.d[3]=Wq; ca.nb[3]=512;
        ca.s[4]=wk_w; ca.d[4]=Wk; ca.nb[4]=512;
        ca.s[5]=wv_w; ca.d[5]=Wv; ca.nb[5]=512;
        ca.s[6]=wo_w; ca.d[6]=Wo; ca.nb[6]=512;
        cvtk<<<dim3(4096, 7), blk, 0, stream>>>(ca);

        GemmArgs ga;
        ga.X[0]=Xq; ga.W[0]=Wq; ga.B[0]=wq_b; ga.O[0]=Qp; ga.mode[0]=0; ga.scale[0]=QSCALE;
        ga.X[1]=Xk; ga.W[1]=Wk; ga.B[1]=wk_b; ga.O[1]=Kp; ga.mode[1]=0; ga.scale[1]=1.0f;
        ga.X[2]=Xv; ga.W[2]=Wv; ga.B[2]=wv_b; ga.O[2]=Vp; ga.mode[2]=0; ga.scale[2]=1.0f;
        gemmk<<<ggrid, gblk, LDSB, stream>>>(ga);

        attn<<<dim3(1024), blk, 0, stream>>>(Qp, Kp, Vp, ctx);

        GemmArgs go;
        for (int i = 0; i < 3; i++) {
            go.X[i]=ctx; go.W[i]=Wo; go.B[i]=wo_b;
            go.O[i]=out; go.mode[i]=2; go.scale[i]=1.0f;
        }
        gemmk<<<ggrid1, gblk, LDSB, stream>>>(go);
    } else {
        // Serial fallback: Xb reused per projection, then as ctx (68 MB).
        ushort* Xb  = (ushort*)d_ws;
        ushort* Wb  = Xb + NE;
        ushort* Wob = Wb + NW;
        ushort* Qp  = Wob + NW;
        ushort* Kp  = Qp + NE;
        ushort* Vp  = Kp + NE;
        ushort* ctx = Xb;

        const float* xs[3] = {q, k, v};
        const float* ws[3] = {wq_w, wk_w, wv_w};
        const float* bs[3] = {wq_b, wk_b, wv_b};
        ushort* os[3] = {Qp, Kp, Vp};
        for (int p = 0; p < 3; p++) {
            CvtArgs c;
            c.s[0]=xs[p]; c.d[0]=Xb; c.nb[0]=4096;
            c.s[1]=ws[p]; c.d[1]=Wb; c.nb[1]=512;
            for (int i = 2; i < 7; i++) { c.s[i]=xs[p]; c.d[i]=Xb; c.nb[i]=0; }
            cvtk<<<dim3(4096, 2), blk, 0, stream>>>(c);
            GemmArgs gg;
            for (int i = 0; i < 3; i++) {
                gg.X[i]=Xb; gg.W[i]=Wb; gg.B[i]=bs[p]; gg.O[i]=os[p];
                gg.mode[i]=0; gg.scale[i]=(p == 0) ? QSCALE : 1.0f;
            }
            gemmk<<<ggrid1, gblk, LDSB, stream>>>(gg);
        }

        attn<<<dim3(1024), blk, 0, stream>>>(Qp, Kp, Vp, ctx);

        CvtArgs c;
        c.s[0]=wo_w; c.d[0]=Wob; c.nb[0]=512;
        for (int i = 1; i < 7; i++) { c.s[i]=wo_w; c.d[i]=Wob; c.nb[i]=0; }
        cvtk<<<dim3(512, 1), blk, 0, stream>>>(c);
        GemmArgs go;
        for (int i = 0; i < 3; i++) {
            go.X[i]=ctx; go.W[i]=Wob; go.B[i]=wo_b;
            go.O[i]=out; go.mode[i]=2; go.scale[i]=1.0f;
        }
        gemmk<<<ggrid1, gblk, LDSB, stream>>>(go);
    }
}

// Round 14
// 320.200 us; speedup vs baseline: 1.0292x; 1.0292x over previous
//
#include <hip/hip_runtime.h>
#include <hip/hip_bf16.h>

typedef __attribute__((ext_vector_type(8))) short bf16x8;
typedef __attribute__((ext_vector_type(4))) short bf16x4;
typedef __attribute__((ext_vector_type(4))) float f32x4;
typedef __attribute__((address_space(3))) ushort lds_ushort;

#define MFMA32(a, b, c) __builtin_amdgcn_mfma_f32_16x16x32_bf16(a, b, c, 0, 0, 0)
#if __has_builtin(__builtin_amdgcn_mfma_f32_16x16x16bf16_1k)
#define HAVE_MFMA16K 1
#define MFMA16K(a, b, c) __builtin_amdgcn_mfma_f32_16x16x16bf16_1k(a, b, c, 0, 0, 0)
#else
#define HAVE_MFMA16K 0
#endif

// async global->LDS, 16B/lane; LDS dest = wave-uniform base + lane*16.
#define ASYNC16(g, l)                                                          \
    __builtin_amdgcn_global_load_lds(                                          \
        (const __attribute__((address_space(1))) unsigned int*)(g),            \
        (__attribute__((address_space(3))) unsigned int*)(l), 16, 0, 0)

// hw transpose read: per 16-lane group reads 128B window as 4x16 bf16
// row-major, lane l gets column (l&15). addr = window_base + (l&15)*8 bytes.
#define TR16(dst, addr, OFF)                                                   \
    asm volatile("ds_read_b64_tr_b16 %0, %1 offset:%2"                         \
                 : "=v"(dst) : "v"(addr), "i"(OFF))

__device__ __forceinline__ ushort f2bf(float f) {
    __hip_bfloat16 h = __float2bfloat16(f);  // RNE
    return *reinterpret_cast<ushort*>(&h);
}
// pack two f32 to bf16 pair in one instruction (T12; no builtin on gfx950).
__device__ __forceinline__ uint cvtpk(float a, float b) {
    uint r;
    asm("v_cvt_pk_bf16_f32 %0, %1, %2" : "=v"(r) : "v"(a), "v"(b));
    return r;
}

// log2(e)/sqrt(64), folded into Q projection -> attn does exp2(score) raw.
#define QSCALE 0.18033688011112042f

// ---------------------------------------------------------------------------
// fp32 -> bf16 convert, multi-range (q,k,v + 4 weights).
// ---------------------------------------------------------------------------
struct CvtArgs { const float* s[7]; ushort* d[7]; int nb[7]; };

__global__ __launch_bounds__(256) void cvtk(CvtArgs a) {
    const int z = blockIdx.y;
    if ((int)blockIdx.x >= a.nb[z]) return;
    const float* s = a.s[z];
    ushort* d = a.d[z];
    const size_t i = (size_t)blockIdx.x * 2048 + threadIdx.x * 8;
    float4 f0 = *(const float4*)&s[i];
    float4 f1 = *(const float4*)&s[i + 4];
    *(ushort4*)&d[i]     = make_ushort4(f2bf(f0.x), f2bf(f0.y), f2bf(f0.z), f2bf(f0.w));
    *(ushort4*)&d[i + 4] = make_ushort4(f2bf(f1.x), f2bf(f1.y), f2bf(f1.z), f2bf(f1.w));
}

// ---------------------------------------------------------------------------
// 128x128 counted-vmcnt bf16 NT GEMM (R11 configuration — session best):
// out = (X@W^T + bias) * scale
//   mode 0: bf16 out [B=4,H=16,S=2048,64]; mode 2: fp32 out [8192,1024].
// BM=BN=128, BK=64, LDS 64KB -> 2 blocks/CU (launch_bounds(512,4)); 8 waves
// (2Mx4N), acc[4][2]. 2 phases/tile x 8 MFMA.
// Phase p in {0,1}: {issue 2 units || ds_read 2 A-rowblocks (+4 B-frags at
// p0)} -> barrier -> lgkmcnt(0) -> setprio(1) -> 8 MFMA -> setprio(0) ->
// [p1: vmcnt] -> barrier.
// vmcnt ledger (1 load/unit; units per tile B0,B1,A0,A1 = seq 4t..4t+3):
// entering tile t: 2 in flight (t+1 B0,B1). p0 issues t+1 A0,A1 (opposite
// buf, safe) -> 4. p1 issues t+2 B0,B1 (same buf; safe: p0-end barrier
// guarantees all waves drained their B-frag lgkmcnt(0) first) -> 6.
// vmcnt(2) at p1 retires exactly tile t+1, leaves t+2 B0,B1. t>=14: issue
// stream exhausted (s>=64) -> full drain vmcnt(0) (tail-race rule from R7).
// NOTE (R12 post-mortem): merging to 1 phase x 16 MFMA regressed +22us —
// it halves A's prefetch cover below HBM latency. 8 MFMA/phase is the
// local optimum of this schedule family.
// Bank swizzle: phys 16B-group = logical^(row&7) on DMA source and reads.
// XCD: t0=(flat&7)*64+flat>>3 (bijective, 512%8==0).
// ---------------------------------------------------------------------------
struct GemmArgs {
    const ushort* X[3]; const ushort* W[3]; const float* B[3];
    void* O[3]; int mode[3]; float scale[3];
};

__global__ __launch_bounds__(512, 4) void gemmk(GemmArgs g) {
    extern __shared__ __attribute__((aligned(16))) ushort smem[];
    // A: [0, 16384) ushorts (2 bufs x 8192); B: [16384, 32768) (2 x 8192).

    const int z = blockIdx.z;
    const ushort* __restrict__ X = g.X[z];
    const ushort* __restrict__ W = g.W[z];
    const float*  __restrict__ bias = g.B[z];
    const int mode = g.mode[z];
    const float scale = g.scale[z];

    const int tid  = threadIdx.x;
    const int lane = tid & 63;
    const int wave = tid >> 6;
    const int quad = (lane >> 4) & 3;
    const int l16  = lane & 15;
    const int wm   = (wave >> 2) * 64;   // 2 M-waves: 64 rows each
    const int wn   = (wave & 3) * 32;    // 4 N-waves: 32 cols each

    const int flat = blockIdx.x + 8 * blockIdx.y;     // 0..511, xcd = flat%8
    const int t0   = (flat & 7) * 64 + (flat >> 3);   // bijective (512%8==0)
    const int m0   = (t0 >> 3) * 128;
    const int n0   = (t0 & 7) * 128;

    f32x4 acc[4][2];
#pragma unroll
    for (int i = 0; i < 4; i++)
#pragma unroll
        for (int j = 0; j < 2; j++) acc[i][j] = (f32x4)0.0f;

    // seq s -> tile s>>2, kind s&3 (0,1 = B half, 2,3 = A half). 1 load/thr.
    auto issue = [&](int s) {
        if (s >= 64) return;
        const int tile = s >> 2;
        const int buf  = tile & 1;
        const int kind = s & 3;
        const int k0   = tile * 64;
        const int row  = tid >> 3;           // 0..63
        const int gp   = (tid & 7) ^ (row & 7);
        if (kind < 2) {
            ASYNC16(&W[(size_t)(n0 + kind * 64 + row) * 1024 + k0 + gp * 8],
                    smem + 16384 + buf * 8192 + kind * 4096 + wave * 512);
        } else {
            const int half = kind - 2;
            ASYNC16(&X[(size_t)(m0 + half * 64 + row) * 1024 + k0 + gp * 8],
                    smem + buf * 8192 + half * 4096 + wave * 512);
        }
    };

    // Prologue: tile0 (4 loads) + tile1 B0,B1 (2); land tile0.
    for (int s = 0; s < 6; s++) issue(s);
    asm volatile("s_waitcnt vmcnt(2)" ::: "memory");
    __builtin_amdgcn_sched_barrier(0);
    __builtin_amdgcn_s_barrier();

    const int sw = l16 & 7;

    for (int t = 0; t < 16; t++) {
        const ushort* A  = smem + (t & 1) * 8192;
        const ushort* Bm = smem + 16384 + (t & 1) * 8192;
        bf16x8 bfrag[2][2];
#pragma unroll
        for (int p = 0; p < 2; p++) {
            issue(4 * t + 2 * p + 6);
            issue(4 * t + 2 * p + 7);
            if (p == 0) {
#pragma unroll
                for (int nj = 0; nj < 2; nj++)
#pragma unroll
                    for (int ks = 0; ks < 2; ks++) {
                        const int br = wn + nj * 16 + l16;
                        bfrag[nj][ks] = *(const bf16x8*)
                            &Bm[(size_t)(br >> 6) * 4096 + (br & 63) * 64
                                + (((ks * 4 + quad) ^ sw) * 8)];
                    }
            }
            bf16x8 af[2][2];
#pragma unroll
            for (int i = 0; i < 2; i++)
#pragma unroll
                for (int ks = 0; ks < 2; ks++) {
                    const int ar = wm + (2 * p + i) * 16 + l16;
                    af[i][ks] = *(const bf16x8*)
                        &A[(size_t)(ar >> 6) * 4096 + (ar & 63) * 64
                           + (((ks * 4 + quad) ^ sw) * 8)];
                }
            __builtin_amdgcn_s_barrier();
            asm volatile("s_waitcnt lgkmcnt(0)" ::: "memory");
            __builtin_amdgcn_sched_barrier(0);
            __builtin_amdgcn_s_setprio(1);
#pragma unroll
            for (int i = 0; i < 2; i++)
#pragma unroll
                for (int nj = 0; nj < 2; nj++) {
                    acc[2 * p + i][nj] = MFMA32(af[i][0], bfrag[nj][0],
                                                acc[2 * p + i][nj]);
                    acc[2 * p + i][nj] = MFMA32(af[i][1], bfrag[nj][1],
                                                acc[2 * p + i][nj]);
                }
            __builtin_amdgcn_s_setprio(0);
            if (p == 1) {
                if (t < 14) {
                    // tile t+1 fully landed; t+2's B0,B1 stay in flight.
                    asm volatile("s_waitcnt vmcnt(2)" ::: "memory");
                } else {
                    // issue stream exhausted: full drain (tail-race fix).
                    asm volatile("s_waitcnt vmcnt(0)" ::: "memory");
                }
                __builtin_amdgcn_sched_barrier(0);
            }
            __builtin_amdgcn_s_barrier();
        }
    }

    // C/D: col = lane&15 (n), row = quad*4 + reg (m).
#pragma unroll
    for (int mi = 0; mi < 4; mi++) {
#pragma unroll
        for (int nj = 0; nj < 2; nj++) {
            const int n  = n0 + wn + nj * 16 + l16;
            const float bb = bias[n];
#pragma unroll
            for (int r = 0; r < 4; r++) {
                const int m = m0 + wm + mi * 16 + quad * 4 + r;
                const float val = (acc[mi][nj][r] + bb) * scale;
                if (mode == 2) {
                    ((float*)g.O[z])[(size_t)m * 1024 + n] = val;
                } else {
                    const int bat = m >> 11, s = m & 2047, h = n >> 6, d = n & 63;
                    ((ushort*)g.O[z])[((size_t)((bat * 16 + h) * 2048 + s)) * 64 + d]
                        = f2bf(val);
                }
            }
        }
    }
}

// ---------------------------------------------------------------------------
// Attention — VERBATIM R8/R10/R11 version (harness-passed at ~92 us; ~97%
// combined MFMA+VALU issue = structural ceiling). st=2, grid 1024, 4/CU.
// ---------------------------------------------------------------------------
__global__ __launch_bounds__(256, 4) void attn(
    const ushort* __restrict__ Qp, const ushort* __restrict__ Kp,
    const ushort* __restrict__ Vp, ushort* __restrict__ ctx)
{
    __shared__ __attribute__((aligned(16))) ushort Ks[2][2 * 64 * 32];  // 2x8KB
    __shared__ __attribute__((aligned(16))) ushort Vs[2][64 * 64];      // 2x8KB

    const int tid  = threadIdx.x;
    const int lane = tid & 63;
    const int wave = tid >> 6;
    const int quad = lane >> 4;
    const int l16  = lane & 15;

    const int id = blockIdx.x;
    const int bh = (id & 7) * 8 + ((id >> 3) & 7);  // XCD-contiguous bh
    const int q0 = (id >> 6) * 128;
    const int b  = bh >> 4, h = bh & 15;

    const ushort* Qg = Qp + ((size_t)bh * 2048 + q0) * 64;
    const ushort* Kg = Kp + (size_t)bh * 2048 * 64;
    const ushort* Vg = Vp + (size_t)bh * 2048 * 64;

    // Loop-invariant Q fragments (B-operand: n=l16=query, k=quad*8+e).
    bf16x8 aq[2][2];
#pragma unroll
    for (int st = 0; st < 2; st++)
#pragma unroll
        for (int kk = 0; kk < 2; kk++)
            aq[st][kk] = *(const bf16x8*)&Qg[(size_t)(wave * 32 + st * 16 + l16) * 64
                                            + kk * 32 + quad * 8];

    f32x4 o[2][4];
#pragma unroll
    for (int st = 0; st < 2; st++)
#pragma unroll
        for (int jd = 0; jd < 4; jd++) o[st][jd] = (f32x4)0.0f;
#if HAVE_MFMA16K
    f32x4 ls[2] = {(f32x4)0.0f, (f32x4)0.0f};  // row sums, o-compatible layout
    union { uint u[2]; bf16x4 v; } ones;
    ones.u[0] = 0x3F803F80u; ones.u[1] = 0x3F803F80u;  // bf16 1.0 x4
#else
    float lsum[2] = {0.f, 0.f};
#endif

    // K tile: natural [half][row][32] layout. V tile: 4x16-subtiled V' via
    // source-swizzled async chunks; global src stays 128B-coalesced per 8 lanes.
    auto stage = [&](int buf, int n0) {
#pragma unroll
        for (int j = 0; j < 2; j++) {
            const int c    = j * 256 + tid;
            const int colq = c & 3;
            const int row  = (c >> 2) & 63;
            const int half = c >> 8;
            ASYNC16(&Kg[(size_t)(n0 + row) * 64 + half * 32 + colq * 8],
                    &Ks[buf][0] + (size_t)(j * 256 + wave * 64) * 8);
        }
#pragma unroll
        for (int j = 0; j < 2; j++) {
            const int c   = j * 256 + tid;
            const int key = ((c >> 5) << 2) | ((c >> 1) & 3);
            const int d   = (((c >> 3) & 3) << 4) | ((c & 1) << 3);
            ASYNC16(&Vg[(size_t)(n0 + key) * 64 + d],
                    &Vs[buf][0] + (size_t)(j * 256 + wave * 64) * 8);
        }
    };

    stage(0, 0);
    int cur = 0;

    for (int n0 = 0; n0 < 2048; n0 += 64) {
        __syncthreads();  // drains vmcnt: buf 'cur' is ready; prev reads done
        if (n0 + 64 < 2048) stage(cur ^ 1, n0 + 64);  // flies under compute

        // ---- S^T: 8 tiles (kb keys x st strips), exp2 + pack in-register ----
        uint pk[4][2][2];
#pragma unroll
        for (int kb = 0; kb < 4; kb++) {
            bf16x8 kf0 = *(const bf16x8*)&Ks[cur][(size_t)(kb * 16 + l16) * 32 + quad * 8];
            bf16x8 kf1 = *(const bf16x8*)&Ks[cur][(size_t)(64 + kb * 16 + l16) * 32 + quad * 8];
#pragma unroll
            for (int st = 0; st < 2; st++) {
                f32x4 s = (f32x4)0.0f;
                s = MFMA32(kf0, aq[st][0], s);
                s = MFMA32(kf1, aq[st][1], s);
                float e0 = __builtin_amdgcn_exp2f(s[0]);
                float e1 = __builtin_amdgcn_exp2f(s[1]);
                float e2 = __builtin_amdgcn_exp2f(s[2]);
                float e3 = __builtin_amdgcn_exp2f(s[3]);
                pk[kb][st][0] = cvtpk(e0, e1);
                pk[kb][st][1] = cvtpk(e2, e3);
#if !HAVE_MFMA16K
                lsum[st] += (e0 + e1) + (e2 + e3);
#endif
            }
        }

#if HAVE_MFMA16K
        // ---- PV: B-frags via hw transpose reads from subtiled V' ----
        const lds_ushort* vp = (const lds_ushort*)&Vs[cur][0] + quad * 256 + l16 * 4;
        bf16x4 vf[4][4];  // [jd][kb]
#define TRISSUE(JD)                                                            \
        TR16(vf[JD][0], vp, (JD) * 128 + 0);                                   \
        TR16(vf[JD][1], vp, (JD) * 128 + 2048);                                \
        TR16(vf[JD][2], vp, (JD) * 128 + 4096);                                \
        TR16(vf[JD][3], vp, (JD) * 128 + 6144);
        TRISSUE(0) TRISSUE(1) TRISSUE(2) TRISSUE(3)

        // Row-sum MFMAs (register-only) fill the tr-read latency window.
#pragma unroll
        for (int kb = 0; kb < 4; kb++) {
#pragma unroll
            for (int st = 0; st < 2; st++) {
                union { uint u[2]; bf16x4 v; } pf;
                pf.u[0] = pk[kb][st][0];
                pf.u[1] = pk[kb][st][1];
                ls[st] = MFMA16K(pf.v, ones.v, ls[st]);
            }
        }

        // counted lgkmcnt: jd group ready when <=12-4*jd outstanding (FIFO,
        // trs are oldest). sched_barrier(0) after each wait (rule #18).
#define PVWAIT(N)                                                              \
        asm volatile("s_waitcnt lgkmcnt(" #N ")" ::: "memory");                \
        __builtin_amdgcn_sched_barrier(0);
#define PVJD(JD)                                                               \
        _Pragma("unroll")                                                      \
        for (int kb = 0; kb < 4; kb++) {                                       \
            _Pragma("unroll")                                                  \
            for (int st = 0; st < 2; st++) {                                   \
                union { uint u[2]; bf16x4 v; } pf;                             \
                pf.u[0] = pk[kb][st][0];                                       \
                pf.u[1] = pk[kb][st][1];                                       \
                o[st][JD] = MFMA16K(pf.v, vf[JD][kb], o[st][JD]);              \
            }                                                                  \
        }
        __builtin_amdgcn_s_setprio(1);
        PVWAIT(12) PVJD(0)
        PVWAIT(8)  PVJD(1)
        PVWAIT(4)  PVJD(2)
        PVWAIT(0)  PVJD(3)
        __builtin_amdgcn_s_setprio(0);
#else
        // Fallback: assemble K=32 A-frags via ds_bpermute, gather V from the
        // subtiled V' with scalar reads, PV with MFMA32. (Correctness path.)
        const int addr0 = 4 * ((2 * (quad & 1)) * 16 + l16);
        const int addr1 = addr0 + 64;
#pragma unroll
        for (int kt = 0; kt < 2; kt++) {
            bf16x8 apf[2];
#pragma unroll
            for (int st = 0; st < 2; st++) {
                union { uint u[4]; bf16x8 v; } t;
#pragma unroll
                for (int j = 0; j < 4; j++) {
                    uint src = (quad & 2) ? pk[kt * 2 + 1][st][j & 1]
                                          : pk[kt * 2][st][j & 1];
                    t.u[j] = (uint)__builtin_amdgcn_ds_bpermute(
                        (j >> 1) ? addr1 : addr0, (int)src);
                }
                apf[st] = t.v;
            }
#pragma unroll
            for (int jd = 0; jd < 4; jd++) {
                union { ushort s[8]; bf16x8 v; } vv;
#pragma unroll
                for (int e = 0; e < 8; e++) {
                    const int key = kt * 32 + quad * 8 + e;
                    const int d   = jd * 16 + l16;
                    vv.s[e] = Vs[cur][(key >> 2) * 256 + (d >> 4) * 64
                                      + (key & 3) * 16 + (d & 15)];
                }
#pragma unroll
                for (int st = 0; st < 2; st++)
                    o[st][jd] = MFMA32(apf[st], vv.v, o[st][jd]);
            }
        }
#endif
        cur ^= 1;
    }

#if HAVE_MFMA16K
    // ls[st][r] is already the row sum for query quad*4+r — no shuffles.
#pragma unroll
    for (int st = 0; st < 2; st++) {
        float inv[4];
#pragma unroll
        for (int r = 0; r < 4; r++) inv[r] = 1.0f / ls[st][r];
#pragma unroll
        for (int jd = 0; jd < 4; jd++) {
#pragma unroll
            for (int r = 0; r < 4; r++) {
                const int s = q0 + wave * 32 + st * 16 + quad * 4 + r;
                ctx[((size_t)(b * 2048 + s)) * 1024 + h * 64 + jd * 16 + l16] =
                    f2bf(o[st][jd][r] * inv[r]);
            }
        }
    }
#else
    // lsum holds per-(l16,quad) partials for query=l16: reduce over quads.
#pragma unroll
    for (int st = 0; st < 2; st++) {
        float lsv = lsum[st];
        lsv += __shfl_xor(lsv, 16, 64);
        lsv += __shfl_xor(lsv, 32, 64);
        float inv[4];
#pragma unroll
        for (int r = 0; r < 4; r++)
            inv[r] = 1.0f / __shfl(lsv, quad * 4 + r, 64);
#pragma unroll
        for (int jd = 0; jd < 4; jd++) {
#pragma unroll
            for (int r = 0; r < 4; r++) {
                const int s = q0 + wave * 32 + st * 16 + quad * 4 + r;
                ctx[((size_t)(b * 2048 + s)) * 1024 + h * 64 + jd * 16 + l16] =
                    f2bf(o[st][jd][r] * inv[r]);
            }
        }
    }
#endif
}

extern "C" void kernel_launch(void* const* d_in, const int* in_sizes, int n_in,
                              void* d_out, int out_size, void* d_ws, size_t ws_size,
                              hipStream_t stream) {
    const float* q    = (const float*)d_in[0];
    const float* k    = (const float*)d_in[1];
    const float* v    = (const float*)d_in[2];
    const float* wq_w = (const float*)d_in[3];
    const float* wq_b = (const float*)d_in[4];
    const float* wk_w = (const float*)d_in[5];
    const float* wk_b = (const float*)d_in[6];
    const float* wv_w = (const float*)d_in[7];
    const float* wv_b = (const float*)d_in[8];
    const float* wo_w = (const float*)d_in[9];
    const float* wo_b = (const float*)d_in[10];
    float* out = (float*)d_out;

    const size_t NE = (size_t)4 * 2048 * 1024;
    const size_t NW = (size_t)1024 * 1024;
    const size_t need_fused = (6 * NE + 4 * NW) * 2;
    const size_t LDSB = 65536;  // 64KB dynamic LDS for gemmk -> 2 blocks/CU

    dim3 blk(256);
    dim3 gblk(512);
    dim3 ggrid(8, 64, 3);   // 512 wgs/z: 64 m-tiles x 8 n-tiles
    dim3 ggrid1(8, 64, 1);

    if (ws_size >= need_fused) {
        ushort* Xq = (ushort*)d_ws;
        ushort* Xk = Xq + NE;
        ushort* Xv = Xk + NE;
        ushort* Wq = Xv + NE;
        ushort* Wk = Wq + NW;
        ushort* Wv = Wk + NW;
        ushort* Wo = Wv + NW;
        ushort* Qp = Wo + NW;
        ushort* Kp = Qp + NE;
        ushort* Vp = Kp + NE;
        ushort* ctx = Xq;

        CvtArgs ca;
        ca.s[0]=q;    ca.d[0]=Xq; ca.nb[0]=4096;
        ca.s[1]=k;    ca.d[1]=Xk; ca.nb[1]=4096;
        ca.s[2]=v;    ca.d[2]=Xv; ca.nb[2]=4096;
        ca.s[3]=wq_w; ca.d[3]=Wq; ca.nb[3]=512;
        ca.s[4]=wk_w; ca.d[4]=Wk; ca.nb[4]=512;
        ca.s[5]=wv_w; ca.d[5]=Wv; ca.nb[5]=512;
        ca.s[6]=wo_w; ca.d[6]=Wo; ca.nb[6]=512;
        cvtk<<<dim3(4096, 7), blk, 0, stream>>>(ca);

        GemmArgs ga;
        ga.X[0]=Xq; ga.W[0]=Wq; ga.B[0]=wq_b; ga.O[0]=Qp; ga.mode[0]=0; ga.scale[0]=QSCALE;
        ga.X[1]=Xk; ga.W[1]=Wk; ga.B[1]=wk_b; ga.O[1]=Kp; ga.mode[1]=0; ga.scale[1]=1.0f;
        ga.X[2]=Xv; ga.W[2]=Wv; ga.B[2]=wv_b; ga.O[2]=Vp; ga.mode[2]=0; ga.scale[2]=1.0f;
        gemmk<<<ggrid, gblk, LDSB, stream>>>(ga);

        attn<<<dim3(1024), blk, 0, stream>>>(Qp, Kp, Vp, ctx);

        GemmArgs go;
        for (int i = 0; i < 3; i++) {
            go.X[i]=ctx; go.W[i]=Wo; go.B[i]=wo_b;
            go.O[i]=out; go.mode[i]=2; go.scale[i]=1.0f;
        }
        gemmk<<<ggrid1, gblk, LDSB, stream>>>(go);
    } else {
        // Serial fallback: Xb reused per projection, then as ctx (68 MB).
        ushort* Xb  = (ushort*)d_ws;
        ushort* Wb  = Xb + NE;
        ushort* Wob = Wb + NW;
        ushort* Qp  = Wob + NW;
        ushort* Kp  = Qp + NE;
        ushort* Vp  = Kp + NE;
        ushort* ctx = Xb;

        const float* xs[3] = {q, k, v};
        const float* ws[3] = {wq_w, wk_w, wv_w};
        const float* bs[3] = {wq_b, wk_b, wv_b};
        ushort* os[3] = {Qp, Kp, Vp};
        for (int p = 0; p < 3; p++) {
            CvtArgs c;
            c.s[0]=xs[p]; c.d[0]=Xb; c.nb[0]=4096;
            c.s[1]=ws[p]; c.d[1]=Wb; c.nb[1]=512;
            for (int i = 2; i < 7; i++) { c.s[i]=xs[p]; c.d[i]=Xb; c.nb[i]=0; }
            cvtk<<<dim3(4096, 2), blk, 0, stream>>>(c);
            GemmArgs gg;
            for (int i = 0; i < 3; i++) {
                gg.X[i]=Xb; gg.W[i]=Wb; gg.B[i]=bs[p]; gg.O[i]=os[p];
                gg.mode[i]=0; gg.scale[i]=(p == 0) ? QSCALE : 1.0f;
            }
            gemmk<<<ggrid1, gblk, LDSB, stream>>>(gg);
        }

        attn<<<dim3(1024), blk, 0, stream>>>(Qp, Kp, Vp, ctx);

        CvtArgs c;
        c.s[0]=wo_w; c.d[0]=Wob; c.nb[0]=512;
        for (int i = 1; i < 7; i++) { c.s[i]=wo_w; c.d[i]=Wob; c.nb[i]=0; }
        cvtk<<<dim3(512, 1), blk, 0, stream>>>(c);
        GemmArgs go;
        for (int i = 0; i < 3; i++) {
            go.X[i]=ctx; go.W[i]=Wob; go.B[i]=wo_b;
            go.O[i]=out; go.mode[i]=2; go.scale[i]=1.0f;
        }
        gemmk<<<ggrid1, gblk, LDSB, stream>>>(go);
    }
}